// Round 4
// baseline (298.190 us; speedup 1.0000x reference)
//
#include <hip/hip_runtime.h>

// SAUCD simp_wt scoring: score[b,m] = clip( sum_l |w|[bin(lmbd[b,m,l+1])] * N[b,m,l] * areas[b,m,l], 0, 2 )
// B=8, M=16, L=131072 -> 128 rows of 131072 elements.
//
// R3: ABLATION ROUND. Three dispatches:
//   k_ctrl1: single-stream 64MB read (m13-style float4 grid-stride)  -> is the path healthy?
//   k_ctrl3: three-stream 201MB aligned read, no binning             -> do 3 streams conflict?
//   saucd_reduce_kernel: real kernel (R1 + 2-group ILP)              -> compute cost on top
// Controls atomicAdd garbage into d_out, which is then memset to 0 BEFORE the real kernel.

#define N_ROWS 128
#define ROW_L 131072
#define BLOCKS_PER_ROW 16
#define TPB 256
#define CHUNK (ROW_L / BLOCKS_PER_ROW)      // 8192 elements per block
#define GROUPS (CHUNK / (TPB * 4))          // 8 float4-groups per thread
#define TOTAL_G (N_ROWS * ROW_L / 4)        // 4,194,304 float4 groups
#define CTRL_BLOCKS 2048

// ---- K1: single-stream read control ----
__global__ __launch_bounds__(256) void k_ctrl1(const float4* __restrict__ p,
                                               float* __restrict__ sink) {
    const size_t stride = (size_t)gridDim.x * blockDim.x;
    float acc = 0.0f;
    for (size_t i = (size_t)blockIdx.x * blockDim.x + threadIdx.x; i < TOTAL_G; i += stride) {
        const float4 v = p[i];
        acc += (v.x + v.y) + (v.z + v.w);
    }
#pragma unroll
    for (int off = 32; off > 0; off >>= 1) acc += __shfl_down(acc, off, 64);
    if ((threadIdx.x & 63) == 0) atomicAdd(&sink[blockIdx.x & 63], acc);
}

// ---- K2: three-stream read control (aligned, no binning) ----
__global__ __launch_bounds__(256) void k_ctrl3(const float4* __restrict__ n,
                                               const float4* __restrict__ l,
                                               const float4* __restrict__ a,
                                               float* __restrict__ sink) {
    const size_t stride = (size_t)gridDim.x * blockDim.x;
    float acc = 0.0f;
    for (size_t i = (size_t)blockIdx.x * blockDim.x + threadIdx.x; i < TOTAL_G; i += stride) {
        const float4 nv = n[i], lv = l[i], av = a[i];
        acc += ((nv.x + lv.x) + (av.x + nv.y)) + ((lv.y + av.y) + (nv.z + lv.z))
             + ((av.z + nv.w) + (lv.w + av.w));
    }
#pragma unroll
    for (int off = 32; off > 0; off >>= 1) acc += __shfl_down(acc, off, 64);
    if ((threadIdx.x & 63) == 0) atomicAdd(&sink[blockIdx.x & 63], acc);
}

// ---- K3: real kernel ----
__device__ __forceinline__ int wbin(float l) {
    // clamp(floor((log(max(l,1e-8)) + 6.0) / 0.105), 0, 63)
    const float logl = __logf(fmaxf(l, 1e-8f));
    const float t = (logl + 6.0f) * 9.52380952380952381f;   // 1/0.105
    return (int)fminf(fmaxf(t, 0.0f), 63.0f);               // clamp-then-trunc == floor-then-clamp
}

__device__ __forceinline__ float dot3(const float* __restrict__ w_abs,
                                      const float4& lv, const float4& nv, const float4& av,
                                      float& a0, float& a1, float& a2, float& a3) {
    a0 = fmaf(w_abs[wbin(lv.x)] * nv.x, av.x, a0);
    a1 = fmaf(w_abs[wbin(lv.y)] * nv.y, av.y, a1);
    a2 = fmaf(w_abs[wbin(lv.z)] * nv.z, av.z, a2);
    a3 = fmaf(w_abs[wbin(lv.w)] * nv.w, av.w, a3);
    return a0;
}

__global__ __launch_bounds__(TPB) void saucd_reduce_kernel(
    const float* __restrict__ weight,      // [64]
    const float* __restrict__ narr,        // [128, 131072]
    const float* __restrict__ lmbd,        // [128, 131073]
    const float* __restrict__ areas,       // [128, 131072]
    float* __restrict__ out)               // [128], pre-zeroed
{
    __shared__ float w_abs[64];
    if (threadIdx.x < 64) w_abs[threadIdx.x] = fabsf(weight[threadIdx.x]);
    __syncthreads();

    const int row = blockIdx.y;
    const size_t blk = (size_t)row * ROW_L + (size_t)blockIdx.x * CHUNK;
    const float4* __restrict__ narr4  = (const float4*)(narr  + blk);
    const float4* __restrict__ areas4 = (const float4*)(areas + blk);
    const float*  __restrict__ lp     = lmbd + (size_t)row * (ROW_L + 1) + 1
                                             + (size_t)blockIdx.x * CHUNK;

    float acc0 = 0.0f, acc1 = 0.0f, acc2 = 0.0f, acc3 = 0.0f;

#pragma unroll
    for (int k = 0; k < GROUPS; k += 2) {      // 2 groups/iter: 6 x 16B loads in flight
        const int g0 = k * TPB + threadIdx.x;
        const int g1 = g0 + TPB;
        const float4 n0 = narr4[g0],  n1 = narr4[g1];
        const float4 a0 = areas4[g0], a1 = areas4[g1];
        float4 l0, l1;
        __builtin_memcpy(&l0, lp + 4 * g0, 16);
        __builtin_memcpy(&l1, lp + 4 * g1, 16);
        dot3(w_abs, l0, n0, a0, acc0, acc1, acc2, acc3);
        dot3(w_abs, l1, n1, a1, acc0, acc1, acc2, acc3);
    }

    float acc = (acc0 + acc1) + (acc2 + acc3);
#pragma unroll
    for (int off = 32; off > 0; off >>= 1) acc += __shfl_down(acc, off, 64);

    __shared__ float wave_sum[TPB / 64];
    const int lane = threadIdx.x & 63;
    const int wid  = threadIdx.x >> 6;
    if (lane == 0) wave_sum[wid] = acc;
    __syncthreads();
    if (threadIdx.x == 0) {
        float s = (wave_sum[0] + wave_sum[1]) + (wave_sum[2] + wave_sum[3]);
        atomicAdd(&out[row], s);   // 16 atomics/row
    }
}

__global__ void saucd_finalize_kernel(float* __restrict__ out, int n) {
    const int i = threadIdx.x + blockIdx.x * blockDim.x;
    if (i < n) out[i] = fminf(fmaxf(out[i], 0.0f), 2.0f);
}

extern "C" void kernel_launch(void* const* d_in, const int* in_sizes, int n_in,
                              void* d_out, int out_size, void* d_ws, size_t ws_size,
                              hipStream_t stream) {
    const float* weight = (const float*)d_in[0];   // [64]
    const float* narr   = (const float*)d_in[1];   // [8,16,131072]
    const float* lmbd   = (const float*)d_in[2];   // [8,16,131073]
    const float* areas  = (const float*)d_in[3];   // [8,16,131072]
    float* out = (float*)d_out;                    // [128] f32

    // Controls first; they pollute d_out, which is then zeroed before the real kernel.
    k_ctrl1<<<CTRL_BLOCKS, 256, 0, stream>>>((const float4*)narr, out);
    k_ctrl3<<<CTRL_BLOCKS, 256, 0, stream>>>((const float4*)narr, (const float4*)lmbd,
                                             (const float4*)areas, out);

    hipMemsetAsync(out, 0, (size_t)out_size * sizeof(float), stream);

    dim3 grid(BLOCKS_PER_ROW, N_ROWS);
    saucd_reduce_kernel<<<grid, TPB, 0, stream>>>(weight, narr, lmbd, areas, out);
    saucd_finalize_kernel<<<1, 128, 0, stream>>>(out, out_size);
}

// Round 5
// 245.768 us; speedup vs baseline: 1.2133x; 1.2133x over previous
//
#include <hip/hip_runtime.h>
#include <stdint.h>

// SAUCD simp_wt scoring: score[b,m] = clip( sum_l |w|[bin(lmbd[b,m,l+1])] * N[b,m,l] * areas[b,m,l], 0, 2 )
// B=8, M=16, L=131072 -> 128 rows.
//
// R4: ALGORITHMIC byte cut. sorted_lmbd is ascending per row and wbin() is
// monotone, so bin(lmbd[l+1]) is a <=64-segment step function per row.
//  K_S: per (row,bin) lower_bound cutoff via binary search (reads ~17 elems/thread)
//  K_R: reduce reading ONLY narr+areas (134 MB vs 201 MB); per-element bin =
//       6-step branchless search over 64 cutoffs in LDS. Bit-exact vs per-element wbin.
//  k_ctrl2: same 2-stream read without binning (roofline control, runs before memset).

#define N_ROWS 128
#define ROW_L 131072
#define BLOCKS_PER_ROW 16
#define TPB 256
#define CHUNK (ROW_L / BLOCKS_PER_ROW)      // 8192 elements per block
#define GROUPS (CHUNK / (TPB * 4))          // 8 float4-groups per thread
#define TOTAL_G (N_ROWS * (ROW_L / 4))      // float4 groups per full stream
#define CTRL_BLOCKS 2048

__device__ __forceinline__ int wbin(float l) {
    // identical to reference binning (empirically bit-exact: absmax 0 in R2/R3)
    const float logl = __logf(fmaxf(l, 1e-8f));
    const float t = (logl + 6.0f) * 9.52380952380952381f;   // 1/0.105
    return (int)fminf(fmaxf(t, 0.0f), 63.0f);
}

// ---- K_S: cutoffs. cut[row][b] = first e in [0,ROW_L) with wbin(lam[e]) >= b ----
__global__ __launch_bounds__(64) void saucd_cutoff_kernel(
    const float* __restrict__ lmbd, int* __restrict__ cut)
{
    const int row = blockIdx.x;
    const int b = threadIdx.x;
    const float* lam = lmbd + (size_t)row * (ROW_L + 1) + 1;   // elements 1..L
    int lo = 0, hi = ROW_L;
    while (lo < hi) {                       // 17 iterations
        const int mid = (lo + hi) >> 1;
        if (wbin(lam[mid]) < b) lo = mid + 1; else hi = mid;
    }
    cut[row * 64 + b] = lo;
}

// largest b with cut[b] <= e  (cut[0]=0 always, so well-defined; branchless)
__device__ __forceinline__ int seg_of(const int* __restrict__ cut, int e) {
    int lo = 0;
#pragma unroll
    for (int s = 32; s; s >>= 1) {          // probes sum to 63: no bounds check needed
        const int t = lo + s;
        lo = (cut[t] <= e) ? t : lo;
    }
    return lo;
}

// ---- k_ctrl2: two-stream read control (no binning) ----
__global__ __launch_bounds__(256) void k_ctrl2(const float4* __restrict__ n,
                                               const float4* __restrict__ a,
                                               float* __restrict__ sink) {
    const size_t stride = (size_t)gridDim.x * blockDim.x;
    float acc = 0.0f;
    for (size_t i = (size_t)blockIdx.x * blockDim.x + threadIdx.x; i < TOTAL_G; i += stride) {
        const float4 nv = n[i], av = a[i];
        acc += ((nv.x + av.x) + (nv.y + av.y)) + ((nv.z + av.z) + (nv.w + av.w));
    }
#pragma unroll
    for (int off = 32; off > 0; off >>= 1) acc += __shfl_down(acc, off, 64);
    if ((threadIdx.x & 63) == 0) atomicAdd(&sink[blockIdx.x & 63], acc);
}

// ---- K_R: main reduce, reads only narr+areas ----
__global__ __launch_bounds__(TPB) void saucd_reduce_kernel(
    const float* __restrict__ weight,      // [64]
    const float* __restrict__ narr,        // [128, 131072]
    const float* __restrict__ areas,       // [128, 131072]
    const int* __restrict__ cut_g,         // [128, 64]
    float* __restrict__ out)               // [128], pre-zeroed
{
    __shared__ float w_abs[64];
    __shared__ int cut[64];
    const int tid = threadIdx.x;
    const int row = blockIdx.y;
    if (tid < 64) {
        w_abs[tid] = fabsf(weight[tid]);
        cut[tid] = cut_g[row * 64 + tid];
    }
    __syncthreads();

    const size_t blk = (size_t)row * ROW_L + (size_t)blockIdx.x * CHUNK;
    const float4* __restrict__ narr4  = (const float4*)(narr  + blk);
    const float4* __restrict__ areas4 = (const float4*)(areas + blk);
    const int ebase = blockIdx.x * CHUNK;   // row-global element index of this block's chunk

    float acc0 = 0.0f, acc1 = 0.0f, acc2 = 0.0f, acc3 = 0.0f;

#pragma unroll
    for (int k = 0; k < GROUPS; k += 2) {   // 2 groups/iter: 4 x 16B loads in flight
        const int g0 = k * TPB + tid;
        const int g1 = g0 + TPB;
        const float4 n0 = narr4[g0],  n1 = narr4[g1];
        const float4 a0 = areas4[g0], a1 = areas4[g1];
        const int e0 = ebase + 4 * g0;
        const int e1 = ebase + 4 * g1;
        acc0 = fmaf(w_abs[seg_of(cut, e0 + 0)] * n0.x, a0.x, acc0);
        acc1 = fmaf(w_abs[seg_of(cut, e0 + 1)] * n0.y, a0.y, acc1);
        acc2 = fmaf(w_abs[seg_of(cut, e0 + 2)] * n0.z, a0.z, acc2);
        acc3 = fmaf(w_abs[seg_of(cut, e0 + 3)] * n0.w, a0.w, acc3);
        acc0 = fmaf(w_abs[seg_of(cut, e1 + 0)] * n1.x, a1.x, acc0);
        acc1 = fmaf(w_abs[seg_of(cut, e1 + 1)] * n1.y, a1.y, acc1);
        acc2 = fmaf(w_abs[seg_of(cut, e1 + 2)] * n1.z, a1.z, acc2);
        acc3 = fmaf(w_abs[seg_of(cut, e1 + 3)] * n1.w, a1.w, acc3);
    }

    float acc = (acc0 + acc1) + (acc2 + acc3);
#pragma unroll
    for (int off = 32; off > 0; off >>= 1) acc += __shfl_down(acc, off, 64);

    __shared__ float wave_sum[TPB / 64];
    const int lane = tid & 63;
    if (lane == 0) wave_sum[tid >> 6] = acc;
    __syncthreads();
    if (tid == 0) {
        float s = (wave_sum[0] + wave_sum[1]) + (wave_sum[2] + wave_sum[3]);
        atomicAdd(&out[row], s);   // 16 atomics/row
    }
}

__global__ void saucd_finalize_kernel(float* __restrict__ out, int n) {
    const int i = threadIdx.x + blockIdx.x * blockDim.x;
    if (i < n) out[i] = fminf(fmaxf(out[i], 0.0f), 2.0f);
}

extern "C" void kernel_launch(void* const* d_in, const int* in_sizes, int n_in,
                              void* d_out, int out_size, void* d_ws, size_t ws_size,
                              hipStream_t stream) {
    const float* weight = (const float*)d_in[0];   // [64]
    const float* narr   = (const float*)d_in[1];   // [8,16,131072]
    const float* lmbd   = (const float*)d_in[2];   // [8,16,131073]
    const float* areas  = (const float*)d_in[3];   // [8,16,131072]
    float* out = (float*)d_out;                    // [128] f32
    int* cut = (int*)d_ws;                         // [128][64] ints = 32 KB scratch

    // cutoffs (tiny) and roofline control; control pollutes out pre-memset
    saucd_cutoff_kernel<<<N_ROWS, 64, 0, stream>>>(lmbd, cut);
    k_ctrl2<<<CTRL_BLOCKS, 256, 0, stream>>>((const float4*)narr, (const float4*)areas, out);

    hipMemsetAsync(out, 0, (size_t)out_size * sizeof(float), stream);

    dim3 grid(BLOCKS_PER_ROW, N_ROWS);
    saucd_reduce_kernel<<<grid, TPB, 0, stream>>>(weight, narr, areas, cut, out);
    saucd_finalize_kernel<<<1, 128, 0, stream>>>(out, out_size);
}

// Round 6
// 195.703 us; speedup vs baseline: 1.5237x; 1.2558x over previous
//
#include <hip/hip_runtime.h>
#include <stdint.h>

// SAUCD simp_wt scoring: score[b,m] = clip( sum_l |w|[bin(lmbd[b,m,l+1])] * N[b,m,l] * areas[b,m,l], 0, 2 )
// B=8, M=16, L=131072 -> 128 rows.
//
// R5: production version of the R4 algorithmic byte-cut.
// sorted_lmbd ascending + wbin monotone => bin(lmbd[l+1]) is a <=64-segment step
// function per row. Pipeline:
//   K_S  cutoff : cut[row][b] = lower_bound(wbin(lam) >= b), 17-step binary search.
//   K_R  reduce : reads ONLY narr+areas (134 MB, the true minimum); per-element
//                 bin via 6-step branchless search over 64 cutoffs in LDS
//                 (bit-exact vs per-element wbin). Writes per-block partials to ws.
//   K_F  final  : sums 16 partials/row, clamps, writes d_out (no atomics/memset).

#define N_ROWS 128
#define ROW_L 131072
#define BLOCKS_PER_ROW 16
#define TPB 256
#define CHUNK (ROW_L / BLOCKS_PER_ROW)      // 8192 elements per block
#define GROUPS (CHUNK / (TPB * 4))          // 8 float4-groups per thread

__device__ __forceinline__ int wbin(float l) {
    // identical to reference binning (empirically bit-exact: absmax 0 in R2-R5)
    const float logl = __logf(fmaxf(l, 1e-8f));
    const float t = (logl + 6.0f) * 9.52380952380952381f;   // 1/0.105
    return (int)fminf(fmaxf(t, 0.0f), 63.0f);               // clamp-then-trunc == floor-then-clamp
}

// ---- K_S: cut[row][b] = first e in [0,ROW_L) with wbin(lam[e]) >= b ----
__global__ __launch_bounds__(64) void saucd_cutoff_kernel(
    const float* __restrict__ lmbd, int* __restrict__ cut)
{
    const int row = blockIdx.x;
    const int b = threadIdx.x;
    const float* lam = lmbd + (size_t)row * (ROW_L + 1) + 1;   // elements 1..L
    int lo = 0, hi = ROW_L;
    while (lo < hi) {                       // 17 iterations
        const int mid = (lo + hi) >> 1;
        if (wbin(lam[mid]) < b) lo = mid + 1; else hi = mid;
    }
    cut[row * 64 + b] = lo;
}

// largest b with cut[b] <= e  (cut[0]==0 always => well-defined; branchless)
__device__ __forceinline__ int seg_of(const int* __restrict__ cut, int e) {
    int lo = 0;
#pragma unroll
    for (int s = 32; s; s >>= 1) {          // probes sum to 63: no bounds check needed
        const int t = lo + s;
        lo = (cut[t] <= e) ? t : lo;
    }
    return lo;
}

// ---- K_R: main reduce, reads only narr+areas; partial per block into ws ----
__global__ __launch_bounds__(TPB) void saucd_reduce_kernel(
    const float* __restrict__ weight,      // [64]
    const float* __restrict__ narr,        // [128, 131072]
    const float* __restrict__ areas,       // [128, 131072]
    const int* __restrict__ cut_g,         // [128, 64]
    float* __restrict__ part)              // [16, 128] partial sums
{
    __shared__ float w_abs[64];
    __shared__ int cut[64];
    const int tid = threadIdx.x;
    const int row = blockIdx.y;
    if (tid < 64) {
        w_abs[tid] = fabsf(weight[tid]);
        cut[tid] = cut_g[row * 64 + tid];
    }
    __syncthreads();

    const size_t blk = (size_t)row * ROW_L + (size_t)blockIdx.x * CHUNK;
    const float4* __restrict__ narr4  = (const float4*)(narr  + blk);
    const float4* __restrict__ areas4 = (const float4*)(areas + blk);
    const int ebase = blockIdx.x * CHUNK;   // row-global element index of chunk start

    float acc0 = 0.0f, acc1 = 0.0f, acc2 = 0.0f, acc3 = 0.0f;

#pragma unroll
    for (int k = 0; k < GROUPS; k += 2) {   // 2 groups/iter: 4 x 16B loads in flight
        const int g0 = k * TPB + tid;
        const int g1 = g0 + TPB;
        const float4 n0 = narr4[g0],  n1 = narr4[g1];
        const float4 a0 = areas4[g0], a1 = areas4[g1];
        const int e0 = ebase + 4 * g0;
        const int e1 = ebase + 4 * g1;
        acc0 = fmaf(w_abs[seg_of(cut, e0 + 0)] * n0.x, a0.x, acc0);
        acc1 = fmaf(w_abs[seg_of(cut, e0 + 1)] * n0.y, a0.y, acc1);
        acc2 = fmaf(w_abs[seg_of(cut, e0 + 2)] * n0.z, a0.z, acc2);
        acc3 = fmaf(w_abs[seg_of(cut, e0 + 3)] * n0.w, a0.w, acc3);
        acc0 = fmaf(w_abs[seg_of(cut, e1 + 0)] * n1.x, a1.x, acc0);
        acc1 = fmaf(w_abs[seg_of(cut, e1 + 1)] * n1.y, a1.y, acc1);
        acc2 = fmaf(w_abs[seg_of(cut, e1 + 2)] * n1.z, a1.z, acc2);
        acc3 = fmaf(w_abs[seg_of(cut, e1 + 3)] * n1.w, a1.w, acc3);
    }

    float acc = (acc0 + acc1) + (acc2 + acc3);
#pragma unroll
    for (int off = 32; off > 0; off >>= 1) acc += __shfl_down(acc, off, 64);

    __shared__ float wave_sum[TPB / 64];
    if ((tid & 63) == 0) wave_sum[tid >> 6] = acc;
    __syncthreads();
    if (tid == 0) {
        // layout part[chunk][row] so K_F's per-lane reads are coalesced
        part[blockIdx.x * N_ROWS + row] =
            (wave_sum[0] + wave_sum[1]) + (wave_sum[2] + wave_sum[3]);
    }
}

// ---- K_F: sum 16 partials per row, clamp, write out ----
__global__ __launch_bounds__(N_ROWS) void saucd_finalize_kernel(
    const float* __restrict__ part, float* __restrict__ out)
{
    const int row = threadIdx.x;
    float s = 0.0f;
#pragma unroll
    for (int k = 0; k < BLOCKS_PER_ROW; ++k)
        s += part[k * N_ROWS + row];        // coalesced across lanes
    out[row] = fminf(fmaxf(s, 0.0f), 2.0f);
}

extern "C" void kernel_launch(void* const* d_in, const int* in_sizes, int n_in,
                              void* d_out, int out_size, void* d_ws, size_t ws_size,
                              hipStream_t stream) {
    const float* weight = (const float*)d_in[0];   // [64]
    const float* narr   = (const float*)d_in[1];   // [8,16,131072]
    const float* lmbd   = (const float*)d_in[2];   // [8,16,131073]
    const float* areas  = (const float*)d_in[3];   // [8,16,131072]
    float* out = (float*)d_out;                    // [128] f32

    int*   cut  = (int*)d_ws;                              // [128*64] = 32 KB
    float* part = (float*)((char*)d_ws + 32 * 1024);       // [16*128] = 8 KB

    saucd_cutoff_kernel<<<N_ROWS, 64, 0, stream>>>(lmbd, cut);

    dim3 grid(BLOCKS_PER_ROW, N_ROWS);
    saucd_reduce_kernel<<<grid, TPB, 0, stream>>>(weight, narr, areas, cut, part);
    saucd_finalize_kernel<<<1, N_ROWS, 0, stream>>>(part, out);
}